// Round 1
// baseline (299.039 us; speedup 1.0000x reference)
//
#include <hip/hip_runtime.h>
#include <hip/hip_bf16.h>
#include <stdint.h>

typedef __hip_bfloat16 bf16;
typedef __attribute__((ext_vector_type(8))) short short8;
typedef __attribute__((ext_vector_type(4))) float f32x4;

#define DEVI __device__ __forceinline__

static constexpr long IMAG_OFF = 8192l * 512;   // offset of imag plane in d_out

DEVI unsigned short f2b(float f) {
  bf16 h = __float2bfloat16(f);
  unsigned short u;
  __builtin_memcpy(&u, &h, 2);
  return u;
}

#define GLD16(g, l) __builtin_amdgcn_global_load_lds( \
    (const __attribute__((address_space(1))) void*)(g), \
    (__attribute__((address_space(3))) void*)(l), 16, 0, 0)

// ---------------------------------------------------------------------------
// Pack x_real/x_imag (fp32) -> xpack bf16 (8192, 1024) = [real | imag]
// ---------------------------------------------------------------------------
__global__ __launch_bounds__(256) void pack_x_kernel(
    const float* __restrict__ xr, const float* __restrict__ xi,
    unsigned short* __restrict__ xp) {
  const int t = blockIdx.x * 256 + threadIdx.x;   // 2,097,152 threads, 4 elems each
  const int m = t >> 8;
  const int d = (t & 255) * 4;
  const float* src = (d < 512) ? (xr + (long)m * 512 + d)
                               : (xi + (long)m * 512 + (d - 512));
  float4 v = *reinterpret_cast<const float4*>(src);
  ushort4 o;
  o.x = f2b(v.x); o.y = f2b(v.y); o.z = f2b(v.z); o.w = f2b(v.w);
  *reinterpret_cast<ushort4*>(xp + (long)m * 1024 + d) = o;
}

// ---------------------------------------------------------------------------
// Build Wbig (1024x1024 bf16) per layer: [[Wr, -Wi], [Wi, Wr]] and packed bias
// ---------------------------------------------------------------------------
struct WArgs {
  const float* wr[5]; const float* wi[5];
  const float* br[5]; const float* bi[5];
};

__global__ __launch_bounds__(256) void pack_w_kernel(
    WArgs a, unsigned short* __restrict__ W, float* __restrict__ bias) {
  const int L = blockIdx.z;
  const int t = blockIdx.x * 256 + threadIdx.x;   // 262144 threads per layer
  const int n = t >> 8;
  const int k = (t & 255) * 4;
  const float* wr = a.wr[L]; const float* wi = a.wi[L];
  const float* src; float sgn = 1.0f;
  if (n < 512) {
    if (k < 512) src = wr + (long)n * 512 + k;
    else { src = wi + (long)n * 512 + (k - 512); sgn = -1.0f; }
  } else {
    if (k < 512) src = wi + (long)(n - 512) * 512 + k;
    else         src = wr + (long)(n - 512) * 512 + (k - 512);
  }
  float4 v = *reinterpret_cast<const float4*>(src);
  ushort4 o;
  o.x = f2b(sgn * v.x); o.y = f2b(sgn * v.y);
  o.z = f2b(sgn * v.z); o.w = f2b(sgn * v.w);
  *reinterpret_cast<ushort4*>(W + (long)L * 1024 * 1024 + (long)n * 1024 + k) = o;
  if (t < 1024)
    bias[L * 1024 + t] = (t < 512) ? a.br[L][t] : a.bi[L][t - 512];
}

// ---------------------------------------------------------------------------
// kmod (B, 2048, 1024): rows 0..1023 = k with imag half negated (scores real),
//                       rows 1024..2047 = k with halves swapped (scores imag)
// ---------------------------------------------------------------------------
__global__ __launch_bounds__(256) void build_kmod_kernel(
    const unsigned short* __restrict__ kin, unsigned short* __restrict__ kmod) {
  const int t = blockIdx.x * 256 + threadIdx.x;   // 2,097,152 threads, 8 elems each
  const int rowg = t >> 7;                        // 0 .. 16383   (b*2048 + tt)
  const int d8 = (t & 127) * 8;
  const int b = rowg >> 11;
  const int tt = rowg & 2047;
  uint4 val;
  if (tt < 1024) {
    val = *reinterpret_cast<const uint4*>(kin + ((long)b * 1024 + tt) * 1024 + d8);
    if (d8 >= 512) {   // negate imag half (8 elems entirely within one half)
      val.x ^= 0x80008000u; val.y ^= 0x80008000u;
      val.z ^= 0x80008000u; val.w ^= 0x80008000u;
    }
  } else {
    const int ts = tt - 1024;
    val = *reinterpret_cast<const uint4*>(kin + ((long)b * 1024 + ts) * 1024 + (d8 ^ 512));
  }
  *reinterpret_cast<uint4*>(kmod + (long)rowg * 1024 + d8) = val;
}

// ---------------------------------------------------------------------------
// GEMM: C[m,n] = sum_k A[m,k] * B[n,k]  (both bf16 row-major, "B^T input")
// 128x128 tile, BK=32, 256 threads = 4 waves (2x2), 4x4 MFMA frags per wave.
// OUTMODE: 0 = bf16 C (ldc=N), 1 = fp32 C (ldc=N), 2 = fp32 split real/imag
// ---------------------------------------------------------------------------
template<int OUTMODE, bool BIAS, bool ACT>
__global__ __launch_bounds__(256) void gemm_kernel(
    const bf16* __restrict__ A, const bf16* __restrict__ Bm,
    void* __restrict__ Cv, const float* __restrict__ bias,
    int M, int N, int K, long sA, long sB, long sC) {
  __shared__ __align__(16) bf16 As[128 * 32];
  __shared__ __align__(16) bf16 Bs[128 * 32];
  const int tid  = threadIdx.x;
  const int wave = tid >> 6, lane = tid & 63;
  const int r = lane & 15, g = lane >> 4;
  const int wr = wave >> 1, wc = wave & 1;
  const int m0 = blockIdx.x * 128, n0 = blockIdx.y * 128;
  const int z  = blockIdx.z;

  const bf16* Ab = A + (long)z * sA;
  const bf16* Bb = Bm + (long)z * sB;

  const int ra = tid >> 2, ca = (tid & 3) * 8;
  const bf16* ga = Ab + (long)(m0 + ra) * K + ca;
  const bf16* gb = Bb + (long)(n0 + ra) * K + ca;
  char* lA = (char*)As + tid * 16;
  char* lB = (char*)Bs + tid * 16;

  f32x4 acc[4][4] = {};

  const int aoff = (wr * 64 + r) * 32 + g * 8;
  const int boff = (wc * 64 + r) * 32 + g * 8;

  for (int kt = 0; kt < K; kt += 32) {
    GLD16(ga + kt,                 lA);
    GLD16(ga + kt + (long)64 * K,  lA + 4096);
    GLD16(gb + kt,                 lB);
    GLD16(gb + kt + (long)64 * K,  lB + 4096);
    __syncthreads();
    short8 af[4], bv[4];
#pragma unroll
    for (int i = 0; i < 4; ++i)
      af[i] = *reinterpret_cast<const short8*>(As + aoff + i * 512);
#pragma unroll
    for (int j = 0; j < 4; ++j)
      bv[j] = *reinterpret_cast<const short8*>(Bs + boff + j * 512);
#pragma unroll
    for (int i = 0; i < 4; ++i)
#pragma unroll
      for (int j = 0; j < 4; ++j)
        acc[i][j] = __builtin_amdgcn_mfma_f32_16x16x32_bf16(af[i], bv[j], acc[i][j], 0, 0, 0);
    __syncthreads();
  }

  // epilogue: C/D mapping col = lane&15, row = (lane>>4)*4 + reg
  const int row0 = m0 + wr * 64 + g * 4;
  const int col0 = n0 + wc * 64 + r;
#pragma unroll
  for (int j = 0; j < 4; ++j) {
    const int col = col0 + j * 16;
    const float bvl = BIAS ? bias[col] : 0.0f;
#pragma unroll
    for (int i = 0; i < 4; ++i) {
      const int rowb = row0 + i * 16;
#pragma unroll
      for (int rg = 0; rg < 4; ++rg) {
        float vv = acc[i][j][rg] + bvl;
        if (ACT) vv = (vv >= 0.0f) ? vv : 0.01f * vv;
        const long rm = rowb + rg;
        if (OUTMODE == 0) {
          bf16* C = (bf16*)Cv + (long)z * sC;
          C[rm * N + col] = __float2bfloat16(vv);
        } else if (OUTMODE == 1) {
          float* C = (float*)Cv + (long)z * sC;
          C[rm * N + col] = vv;
        } else {
          float* O = (float*)Cv;
          if (col < 512) O[rm * 512 + col] = vv;
          else           O[IMAG_OFF + rm * 512 + (col - 512)] = vv;
        }
      }
    }
  }
}

// ---------------------------------------------------------------------------
// Row softmax of |scores|/sqrt(512): scores (row, 2048) fp32 [re(1024)|im(1024)]
// -> attn (row, 1024) bf16.   One 256-thread block per row.
// ---------------------------------------------------------------------------
DEVI float wred_max(float v) {
#pragma unroll
  for (int o = 32; o > 0; o >>= 1) v = fmaxf(v, __shfl_xor(v, o));
  return v;
}
DEVI float wred_sum(float v) {
#pragma unroll
  for (int o = 32; o > 0; o >>= 1) v += __shfl_xor(v, o);
  return v;
}

__global__ __launch_bounds__(256) void softmax_kernel(
    const float* __restrict__ sc, unsigned short* __restrict__ attn) {
  const int row = blockIdx.x;
  const int tid = threadIdx.x;
  const int wave = tid >> 6, lane = tid & 63;
  const float* sp = sc + (long)row * 2048;
  float4 re = *reinterpret_cast<const float4*>(sp + tid * 4);
  float4 im = *reinterpret_cast<const float4*>(sp + 1024 + tid * 4);
  const float scale = 0.044194173824159216f;   // 1/sqrt(512)
  float mg[4];
  mg[0] = sqrtf(re.x * re.x + im.x * im.x) * scale;
  mg[1] = sqrtf(re.y * re.y + im.y * im.y) * scale;
  mg[2] = sqrtf(re.z * re.z + im.z * im.z) * scale;
  mg[3] = sqrtf(re.w * re.w + im.w * im.w) * scale;
  float mx = fmaxf(fmaxf(mg[0], mg[1]), fmaxf(mg[2], mg[3]));
  mx = wred_max(mx);
  __shared__ float sred[8];
  if (lane == 0) sred[wave] = mx;
  __syncthreads();
  mx = fmaxf(fmaxf(sred[0], sred[1]), fmaxf(sred[2], sred[3]));
  float e[4];
  float s = 0.0f;
#pragma unroll
  for (int u = 0; u < 4; ++u) { e[u] = expf(mg[u] - mx); s += e[u]; }
  s = wred_sum(s);
  if (lane == 0) sred[4 + wave] = s;
  __syncthreads();
  s = sred[4] + sred[5] + sred[6] + sred[7];
  const float inv = 1.0f / s;
  ushort4 o;
  o.x = f2b(e[0] * inv); o.y = f2b(e[1] * inv);
  o.z = f2b(e[2] * inv); o.w = f2b(e[3] * inv);
  *reinterpret_cast<ushort4*>(attn + (long)row * 1024 + tid * 4) = o;
}

// ---------------------------------------------------------------------------
// Per-batch transpose: vt[b][d][t] = v[b*1024 + t][d]   (bf16)
// ---------------------------------------------------------------------------
__global__ void transpose_kernel(const unsigned short* __restrict__ v,
                                 unsigned short* __restrict__ vt) {
  __shared__ unsigned short tile[32][33];
  const int b = blockIdx.z;
  const int t0 = blockIdx.x * 32, d0 = blockIdx.y * 32;
  const int tx = threadIdx.x, ty = threadIdx.y;   // 32 x 8
#pragma unroll
  for (int i = 0; i < 32; i += 8)
    tile[ty + i][tx] = v[((long)b * 1024 + t0 + ty + i) * 1024 + d0 + tx];
  __syncthreads();
#pragma unroll
  for (int i = 0; i < 32; i += 8)
    vt[((long)b * 1024 + d0 + ty + i) * 1024 + t0 + tx] = tile[tx][ty + i];
}

// ---------------------------------------------------------------------------
extern "C" void kernel_launch(void* const* d_in, const int* in_sizes, int n_in,
                              void* d_out, int out_size, void* d_ws, size_t ws_size,
                              hipStream_t stream) {
  const float* xr = (const float*)d_in[0];
  const float* xi = (const float*)d_in[1];
  WArgs wa;
  for (int L = 0; L < 5; ++L) {
    wa.wr[L] = (const float*)d_in[2 + 4 * L + 0];
    wa.wi[L] = (const float*)d_in[2 + 4 * L + 1];
    wa.br[L] = (const float*)d_in[2 + 4 * L + 2];
    wa.bi[L] = (const float*)d_in[2 + 4 * L + 3];
  }

  char* ws = (char*)d_ws;
  size_t off = 0;
  auto alloc = [&](size_t bytes) {
    char* p = ws + off;
    off += (bytes + 255) & ~(size_t)255;
    return p;
  };
  unsigned short* W    = (unsigned short*)alloc(5l * 1024 * 1024 * 2);
  float*          bias = (float*)         alloc(5l * 1024 * 4);
  unsigned short* xp   = (unsigned short*)alloc(8192l * 1024 * 2);  // reused as attn
  unsigned short* y    = (unsigned short*)alloc(8192l * 1024 * 2);
  unsigned short* q    = (unsigned short*)alloc(8192l * 1024 * 2);  // reused as weighted
  unsigned short* k    = (unsigned short*)alloc(8192l * 1024 * 2);
  unsigned short* v    = (unsigned short*)alloc(8192l * 1024 * 2);
  unsigned short* kmod = (unsigned short*)alloc(8l * 2048 * 1024 * 2);
  float*          sc   = (float*)         alloc(8l * 1024 * 2048 * 4);
  unsigned short* vt   = (unsigned short*)alloc(8l * 1024 * 1024 * 2);
  (void)ws_size; (void)in_sizes; (void)n_in; (void)out_size;

  pack_x_kernel<<<8192, 256, 0, stream>>>(xr, xi, xp);
  pack_w_kernel<<<dim3(1024, 1, 5), 256, 0, stream>>>(wa, W, bias);

  // l1 (+bias, complex leaky relu)
  gemm_kernel<0, true, true><<<dim3(64, 8, 1), 256, 0, stream>>>(
      (const bf16*)xp, (const bf16*)W, y, bias, 8192, 1024, 1024, 0, 0, 0);
  // q, k, v (+bias)
  gemm_kernel<0, true, false><<<dim3(64, 8, 1), 256, 0, stream>>>(
      (const bf16*)y, (const bf16*)(W + 1l * 1024 * 1024), q, bias + 1024,
      8192, 1024, 1024, 0, 0, 0);
  gemm_kernel<0, true, false><<<dim3(64, 8, 1), 256, 0, stream>>>(
      (const bf16*)y, (const bf16*)(W + 2l * 1024 * 1024), k, bias + 2048,
      8192, 1024, 1024, 0, 0, 0);
  gemm_kernel<0, true, false><<<dim3(64, 8, 1), 256, 0, stream>>>(
      (const bf16*)y, (const bf16*)(W + 3l * 1024 * 1024), v, bias + 3072,
      8192, 1024, 1024, 0, 0, 0);

  build_kmod_kernel<<<8192, 256, 0, stream>>>(k, kmod);

  // scores: per batch (1024 x 2048) = q_b @ kmod_b^T, fp32 out
  gemm_kernel<1, false, false><<<dim3(8, 16, 8), 256, 0, stream>>>(
      (const bf16*)q, (const bf16*)kmod, sc, nullptr,
      1024, 2048, 1024, 1024l * 1024, 2048l * 1024, 1024l * 2048);

  softmax_kernel<<<8192, 256, 0, stream>>>(sc, xp /* attn */);

  transpose_kernel<<<dim3(32, 32, 8), dim3(32, 8), 0, stream>>>(v, vt);

  // weighted: per batch (1024 x 1024) = attn_b @ vt_b^T, bf16 out
  gemm_kernel<0, false, false><<<dim3(8, 8, 8), 256, 0, stream>>>(
      (const bf16*)xp, (const bf16*)vt, q /* weighted */, nullptr,
      1024, 1024, 1024, 1024l * 1024, 1024l * 1024, 1024l * 1024);

  // l2 (+bias), split real/imag fp32 straight into d_out
  gemm_kernel<2, true, false><<<dim3(64, 8, 1), 256, 0, stream>>>(
      (const bf16*)q, (const bf16*)(W + 4l * 1024 * 1024), d_out, bias + 4096,
      8192, 1024, 1024, 0, 0, 0);
}

// Round 2
// 261.268 us; speedup vs baseline: 1.1446x; 1.1446x over previous
//
#include <hip/hip_runtime.h>
#include <hip/hip_bf16.h>
#include <stdint.h>

typedef __hip_bfloat16 bf16;
typedef __attribute__((ext_vector_type(8))) short short8;
typedef __attribute__((ext_vector_type(4))) float f32x4;

#define DEVI __device__ __forceinline__

static constexpr long IMAG_OFF = 8192l * 512;   // offset of imag plane in d_out

DEVI unsigned short f2b(float f) {
  bf16 h = __float2bfloat16(f);
  unsigned short u;
  __builtin_memcpy(&u, &h, 2);
  return u;
}

#define GLD16(g, l) __builtin_amdgcn_global_load_lds( \
    (const __attribute__((address_space(1))) void*)(g), \
    (__attribute__((address_space(3))) void*)(l), 16, 0, 0)

// ---------------------------------------------------------------------------
// Pack x_real/x_imag (fp32) -> xpack bf16 (8192, 1024) = [real | imag]
// ---------------------------------------------------------------------------
__global__ __launch_bounds__(256) void pack_x_kernel(
    const float* __restrict__ xr, const float* __restrict__ xi,
    unsigned short* __restrict__ xp) {
  const int t = blockIdx.x * 256 + threadIdx.x;
  const int m = t >> 8;
  const int d = (t & 255) * 4;
  const float* src = (d < 512) ? (xr + (long)m * 512 + d)
                               : (xi + (long)m * 512 + (d - 512));
  float4 v = *reinterpret_cast<const float4*>(src);
  ushort4 o;
  o.x = f2b(v.x); o.y = f2b(v.y); o.z = f2b(v.z); o.w = f2b(v.w);
  *reinterpret_cast<ushort4*>(xp + (long)m * 1024 + d) = o;
}

// ---------------------------------------------------------------------------
// Build Wbig (1024x1024 bf16) per layer: [[Wr, -Wi], [Wi, Wr]] and packed bias
// ---------------------------------------------------------------------------
struct WArgs {
  const float* wr[5]; const float* wi[5];
  const float* br[5]; const float* bi[5];
};

__global__ __launch_bounds__(256) void pack_w_kernel(
    WArgs a, unsigned short* __restrict__ W, float* __restrict__ bias) {
  const int L = blockIdx.z;
  const int t = blockIdx.x * 256 + threadIdx.x;
  const int n = t >> 8;
  const int k = (t & 255) * 4;
  const float* wr = a.wr[L]; const float* wi = a.wi[L];
  const float* src; float sgn = 1.0f;
  if (n < 512) {
    if (k < 512) src = wr + (long)n * 512 + k;
    else { src = wi + (long)n * 512 + (k - 512); sgn = -1.0f; }
  } else {
    if (k < 512) src = wi + (long)(n - 512) * 512 + k;
    else         src = wr + (long)(n - 512) * 512 + (k - 512);
  }
  float4 v = *reinterpret_cast<const float4*>(src);
  ushort4 o;
  o.x = f2b(sgn * v.x); o.y = f2b(sgn * v.y);
  o.z = f2b(sgn * v.z); o.w = f2b(sgn * v.w);
  *reinterpret_cast<ushort4*>(W + (long)L * 1024 * 1024 + (long)n * 1024 + k) = o;
  if (t < 1024)
    bias[L * 1024 + t] = (t < 512) ? a.br[L][t] : a.bi[L][t - 512];
}

// ---------------------------------------------------------------------------
// GEMM: C[m,n] = sum_k A[m,k] * B[n,k]  (bf16 row-major, B^T input)
// Tile 128(M) x 256(N), BK=32, 512 threads = 8 waves (2M x 4N),
// per-wave 64x64 out = 4x4 fragments. Double-buffered LDS, 1 barrier/iter.
// MFMA operands swapped -> lane holds 4 consecutive COLUMNS -> vector stores.
// OM: 0 = bf16 C (ldc=N)
//     2 = fp32 split real/imag into d_out
//     3 = |complex| * 1/sqrt(512), interleaved re/im rows -> fp32 (ldc=1024)
//     4 = fused QKV epilogue (q plain, k -> interleaved kmod, v plain)
// ---------------------------------------------------------------------------
template<int OM, bool BIAS, bool ACT>
__global__ __launch_bounds__(512) void gemm2_kernel(
    const bf16* __restrict__ A, const bf16* __restrict__ Bm,
    void* __restrict__ C0, void* __restrict__ C1, void* __restrict__ C2,
    const float* __restrict__ bias,
    int N, int K, long sA, long sB, long sC) {
  __shared__ __align__(16) bf16 As[2][128 * 32];
  __shared__ __align__(16) bf16 Bs[2][256 * 32];
  const int tid  = threadIdx.x;
  const int lane = tid & 63, wave = tid >> 6;
  const int r = lane & 15, g = lane >> 4;
  const int wr = wave >> 2, wc = wave & 3;
  const int m0 = blockIdx.x * 128, n0 = blockIdx.y * 256;
  const int z  = blockIdx.z;

  const bf16* Ab = A  + (long)z * sA;
  const bf16* Bb = Bm + (long)z * sB;
  const bf16* ga = Ab + (long)(m0 + (tid >> 2)) * K + (tid & 3) * 8;
  const bf16* gb = Bb + (long)(n0 + (tid >> 2)) * K + (tid & 3) * 8;
  char* lA = (char*)As + tid * 16;
  char* lB = (char*)Bs + tid * 16;
  const long gb2 = (long)128 * K;

  f32x4 acc[4][4] = {};
  const int aoff = (wr * 64 + r) * 32 + g * 8;
  const int boff = (wc * 64 + r) * 32 + g * 8;

#define STAGE2(buf, kt) do { \
    GLD16(ga + (kt), lA + (buf) * 8192); \
    GLD16(gb + (kt), lB + (buf) * 16384); \
    GLD16(gb + (kt) + gb2, lB + (buf) * 16384 + 8192); } while (0)

  STAGE2(0, 0);
  __syncthreads();
  int cur = 0;
  for (int kt = 32; kt <= K; kt += 32) {
    if (kt < K) STAGE2(cur ^ 1, kt);
    const bf16* Ac = As[cur];
    const bf16* Bc = Bs[cur];
    short8 af[4], bv[4];
#pragma unroll
    for (int i = 0; i < 4; ++i)
      af[i] = *reinterpret_cast<const short8*>(Ac + aoff + i * 512);
#pragma unroll
    for (int j = 0; j < 4; ++j)
      bv[j] = *reinterpret_cast<const short8*>(Bc + boff + j * 512);
#pragma unroll
    for (int i = 0; i < 4; ++i)
#pragma unroll
      for (int j = 0; j < 4; ++j)
        acc[i][j] = __builtin_amdgcn_mfma_f32_16x16x32_bf16(bv[j], af[i], acc[i][j], 0, 0, 0);
    __syncthreads();
    cur ^= 1;
  }
#undef STAGE2

  // Epilogue: D = mfma(B_frag, A_frag) -> row(m) = lane&15, col(n) = g*4+reg
  const int rowbase = m0 + wr * 64 + r;
  const int colbase = n0 + wc * 64 + g * 4;
#pragma unroll
  for (int i = 0; i < 4; ++i) {
    const long rm = rowbase + i * 16;
#pragma unroll
    for (int j = 0; j < 4; ++j) {
      const int cn = colbase + j * 16;
      float4 f;
      f.x = acc[i][j][0]; f.y = acc[i][j][1];
      f.z = acc[i][j][2]; f.w = acc[i][j][3];
      if (BIAS) {
        float4 b4 = *reinterpret_cast<const float4*>(bias + cn);
        f.x += b4.x; f.y += b4.y; f.z += b4.z; f.w += b4.w;
      }
      if (ACT) {
        f.x = (f.x >= 0.f) ? f.x : 0.01f * f.x;
        f.y = (f.y >= 0.f) ? f.y : 0.01f * f.y;
        f.z = (f.z >= 0.f) ? f.z : 0.01f * f.z;
        f.w = (f.w >= 0.f) ? f.w : 0.01f * f.w;
      }
      if (OM == 0) {
        unsigned short* C = (unsigned short*)C0 + (long)z * sC;
        ushort4 o; o.x = f2b(f.x); o.y = f2b(f.y); o.z = f2b(f.z); o.w = f2b(f.w);
        *reinterpret_cast<ushort4*>(C + rm * N + cn) = o;
      } else if (OM == 2) {
        float* O = (float*)C0;
        if (cn < 512) *reinterpret_cast<float4*>(O + rm * 512 + cn) = f;
        else          *reinterpret_cast<float4*>(O + IMAG_OFF + rm * 512 + (cn - 512)) = f;
      } else if (OM == 3) {
        float* S = (float*)C0 + (long)z * sC;
        const float scale = 0.044194173824159216f;   // 1/sqrt(512)
        float2 mg;
        mg.x = sqrtf(f.x * f.x + f.y * f.y) * scale;
        mg.y = sqrtf(f.z * f.z + f.w * f.w) * scale;
        *reinterpret_cast<float2*>(S + rm * 1024 + (cn >> 1)) = mg;
      } else if (OM == 4) {
        if (cn < 1024) {            // q
          unsigned short* Q = (unsigned short*)C0;
          ushort4 o; o.x = f2b(f.x); o.y = f2b(f.y); o.z = f2b(f.z); o.w = f2b(f.w);
          *reinterpret_cast<ushort4*>(Q + rm * 1024 + cn) = o;
        } else if (cn < 2048) {     // k -> interleaved kmod
          const int d = cn - 1024;
          const int b = (int)(rm >> 10), t = (int)(rm & 1023);
          unsigned short* KM = (unsigned short*)C1;
          const float s = (d < 512) ? 1.0f : -1.0f;
          ushort4 o1, o2;
          o1.x = f2b(s * f.x); o1.y = f2b(s * f.y);
          o1.z = f2b(s * f.z); o1.w = f2b(s * f.w);
          o2.x = f2b(f.x); o2.y = f2b(f.y); o2.z = f2b(f.z); o2.w = f2b(f.w);
          // row 2t: Re-transform [kr | -ki]; row 2t+1: Im-transform [ki | kr]
          *reinterpret_cast<ushort4*>(KM + ((long)(b << 11) + 2 * t)     * 1024 + d)          = o1;
          *reinterpret_cast<ushort4*>(KM + ((long)(b << 11) + 2 * t + 1) * 1024 + (d ^ 512))  = o2;
        } else {                    // v
          unsigned short* V = (unsigned short*)C2;
          ushort4 o; o.x = f2b(f.x); o.y = f2b(f.y); o.z = f2b(f.z); o.w = f2b(f.w);
          *reinterpret_cast<ushort4*>(V + rm * 1024 + (cn - 2048)) = o;
        }
      }
    }
  }
}

// ---------------------------------------------------------------------------
// Row softmax of mag (row, 1024) fp32 -> attn (row, 1024) bf16.
// One 256-thread block per row; mag already scaled by 1/sqrt(512).
// ---------------------------------------------------------------------------
DEVI float wred_max(float v) {
#pragma unroll
  for (int o = 32; o > 0; o >>= 1) v = fmaxf(v, __shfl_xor(v, o));
  return v;
}
DEVI float wred_sum(float v) {
#pragma unroll
  for (int o = 32; o > 0; o >>= 1) v += __shfl_xor(v, o);
  return v;
}

__global__ __launch_bounds__(256) void softmax_kernel(
    const float* __restrict__ mag, unsigned short* __restrict__ attn) {
  const int row = blockIdx.x;
  const int tid = threadIdx.x;
  const int wave = tid >> 6, lane = tid & 63;
  float4 m4 = *reinterpret_cast<const float4*>(mag + (long)row * 1024 + tid * 4);
  float mx = fmaxf(fmaxf(m4.x, m4.y), fmaxf(m4.z, m4.w));
  mx = wred_max(mx);
  __shared__ float sred[8];
  if (lane == 0) sred[wave] = mx;
  __syncthreads();
  mx = fmaxf(fmaxf(sred[0], sred[1]), fmaxf(sred[2], sred[3]));
  float e[4];
  e[0] = expf(m4.x - mx); e[1] = expf(m4.y - mx);
  e[2] = expf(m4.z - mx); e[3] = expf(m4.w - mx);
  float s = e[0] + e[1] + e[2] + e[3];
  s = wred_sum(s);
  if (lane == 0) sred[4 + wave] = s;
  __syncthreads();
  s = sred[4] + sred[5] + sred[6] + sred[7];
  const float inv = 1.0f / s;
  ushort4 o;
  o.x = f2b(e[0] * inv); o.y = f2b(e[1] * inv);
  o.z = f2b(e[2] * inv); o.w = f2b(e[3] * inv);
  *reinterpret_cast<ushort4*>(attn + (long)row * 1024 + tid * 4) = o;
}

// ---------------------------------------------------------------------------
// Per-batch transpose: vt[b][d][t] = v[b*1024 + t][d]   (bf16)
// ---------------------------------------------------------------------------
__global__ void transpose_kernel(const unsigned short* __restrict__ v,
                                 unsigned short* __restrict__ vt) {
  __shared__ unsigned short tile[32][33];
  const int b = blockIdx.z;
  const int t0 = blockIdx.x * 32, d0 = blockIdx.y * 32;
  const int tx = threadIdx.x, ty = threadIdx.y;   // 32 x 8
#pragma unroll
  for (int i = 0; i < 32; i += 8)
    tile[ty + i][tx] = v[((long)b * 1024 + t0 + ty + i) * 1024 + d0 + tx];
  __syncthreads();
#pragma unroll
  for (int i = 0; i < 32; i += 8)
    vt[((long)b * 1024 + d0 + ty + i) * 1024 + t0 + tx] = tile[tx][ty + i];
}

// ---------------------------------------------------------------------------
extern "C" void kernel_launch(void* const* d_in, const int* in_sizes, int n_in,
                              void* d_out, int out_size, void* d_ws, size_t ws_size,
                              hipStream_t stream) {
  const float* xr = (const float*)d_in[0];
  const float* xi = (const float*)d_in[1];
  WArgs wa;
  for (int L = 0; L < 5; ++L) {
    wa.wr[L] = (const float*)d_in[2 + 4 * L + 0];
    wa.wi[L] = (const float*)d_in[2 + 4 * L + 1];
    wa.br[L] = (const float*)d_in[2 + 4 * L + 2];
    wa.bi[L] = (const float*)d_in[2 + 4 * L + 3];
  }

  char* ws = (char*)d_ws;
  size_t off = 0;
  auto alloc = [&](size_t bytes) {
    char* p = ws + off;
    off += (bytes + 255) & ~(size_t)255;
    return p;
  };
  unsigned short* W    = (unsigned short*)alloc(5l * 1024 * 1024 * 2);
  float*          bias = (float*)         alloc(5l * 1024 * 4);
  unsigned short* xp   = (unsigned short*)alloc(8192l * 1024 * 2);  // reused as attn
  unsigned short* y    = (unsigned short*)alloc(8192l * 1024 * 2);
  unsigned short* q    = (unsigned short*)alloc(8192l * 1024 * 2);  // reused as weighted
  unsigned short* kmod = (unsigned short*)alloc(8l * 2048 * 1024 * 2);
  unsigned short* v    = (unsigned short*)alloc(8192l * 1024 * 2);
  unsigned short* vt   = (unsigned short*)alloc(8l * 1024 * 1024 * 2);
  float*          mag  = (float*)         alloc(8l * 1024 * 1024 * 4);
  (void)ws_size; (void)in_sizes; (void)n_in; (void)out_size;

  pack_x_kernel<<<8192, 256, 0, stream>>>(xr, xi, xp);
  pack_w_kernel<<<dim3(1024, 1, 5), 256, 0, stream>>>(wa, W, bias);

  // l1 (+bias, complex leaky relu): (8192x1024) @ W0^T
  gemm2_kernel<0, true, true><<<dim3(64, 4, 1), 512, 0, stream>>>(
      (const bf16*)xp, (const bf16*)W, y, nullptr, nullptr, bias,
      1024, 1024, 0, 0, 0);

  // fused q,k,v (+bias): (8192x1024) @ [W1;W2;W3]^T, N=3072
  gemm2_kernel<4, true, false><<<dim3(64, 12, 1), 512, 0, stream>>>(
      (const bf16*)y, (const bf16*)(W + 1l * 1024 * 1024), q, kmod, v,
      bias + 1024, 3072, 1024, 0, 0, 0);

  // scores -> |.|/sqrt(512): per batch (1024 x 2048) = q_b @ kmod_b^T, mag out
  gemm2_kernel<3, false, false><<<dim3(8, 8, 8), 512, 0, stream>>>(
      (const bf16*)q, (const bf16*)kmod, mag, nullptr, nullptr, nullptr,
      2048, 1024, 1024l * 1024, 2048l * 1024, 1024l * 1024);

  softmax_kernel<<<8192, 256, 0, stream>>>(mag, xp /* attn */);

  transpose_kernel<<<dim3(32, 32, 8), dim3(32, 8), 0, stream>>>(v, vt);

  // weighted: per batch (1024 x 1024) = attn_b @ vt_b^T, bf16 out
  gemm2_kernel<0, false, false><<<dim3(8, 4, 8), 512, 0, stream>>>(
      (const bf16*)xp, (const bf16*)vt, q /* weighted */, nullptr, nullptr,
      nullptr, 1024, 1024, 1024l * 1024, 1024l * 1024, 1024l * 1024);

  // l2 (+bias), split real/imag fp32 straight into d_out
  gemm2_kernel<2, true, false><<<dim3(64, 4, 1), 512, 0, stream>>>(
      (const bf16*)q, (const bf16*)(W + 4l * 1024 * 1024), d_out, nullptr,
      nullptr, bias + 4096, 1024, 1024, 0, 0, 0);
}